// Round 9
// baseline (473.707 us; speedup 1.0000x reference)
//
#include <hip/hip_runtime.h>
#include <string.h>

// Exact k-th order statistic + mask, fp32, n = 64*1024*1024.
// Decomposed design:
//   k1 mask_only : uint4 read -> 4 compares -> NT float4 store (+chi count)
//   k2 extract   : read-only re-read, ballot-compact bracketed candidates
//   flagcomp     : EXACT bracket verification from k1/k2 counts
//   two 10-bit selects over the ~9MB candidate array -> exact threshold
//   fixup        : scatter 1.0f for candidates >= thr
//   fallback     : proven 3-pass radix select, always enqueued, flag-gated
//
// state: [2]=chi [3]=flag [4]=r' [5]=chunkA [6]=rA [7]=binB [8]=rB
//        [9]=fb_thr [10..15]=fb chain [16]=Nc [17]=max_ccnt

#define N_STATE  32
#define HA_OFF   32
#define HB_OFF   (HA_OFF + 1024)
#define FB1_OFF  (HB_OFF + 1024)
#define FB2_OFF  (FB1_OFF + 4096)
#define FB3_OFF  (FB2_OFF + 4096)
#define FIXED_Z  (FB3_OFF + 256)          // ints zeroed per call (~42 KB)
#define CNTW_OFF FIXED_Z                  // 8192 per-wave counts (no zero)
#define NWAVES   8192
#define CAND_OFF (CNTW_OFF + NWAVES)
#define SEG      2048u

#define FB_WS_INTS (16 + 4096 + 4096 + 256)

typedef float vfloat4 __attribute__((ext_vector_type(4)));

__device__ __forceinline__ unsigned map_bits(unsigned raw) {
    return (raw & 0x80000000u) ? ~raw : (raw | 0x80000000u);
}

// ---------------- tiny workspace zeroing ----------------
__global__ void __launch_bounds__(256)
zero_small(uint4* __restrict__ p, int n16)
{
    int i = blockIdx.x * 256 + threadIdx.x;
    int s = gridDim.x * 256;
    uint4 z = make_uint4(0u, 0u, 0u, 0u);
    for (; i < n16; i += s) p[i] = z;
}

// ---------------- k1: pure streaming mask (copy-probe shape) ----------------
__global__ void __launch_bounds__(256)
mask_only(const uint4* __restrict__ x, int n4, vfloat4* __restrict__ out,
          unsigned* __restrict__ st, unsigned hi_u)
{
    const unsigned lane = threadIdx.x & 63u;
    unsigned chi = 0;
    int idx = blockIdx.x * 256 + threadIdx.x;
    int S = gridDim.x * 256;
    for (int i = idx; i < n4; i += S) {
        uint4 v = x[i];
        vfloat4 o;
        bool g0 = map_bits(v.x) >= hi_u;
        bool g1 = map_bits(v.y) >= hi_u;
        bool g2 = map_bits(v.z) >= hi_u;
        bool g3 = map_bits(v.w) >= hi_u;
        o[0] = g0 ? 1.0f : 0.0f;
        o[1] = g1 ? 1.0f : 0.0f;
        o[2] = g2 ? 1.0f : 0.0f;
        o[3] = g3 ? 1.0f : 0.0f;
        chi += (g0 ? 1u : 0u) + (g1 ? 1u : 0u) + (g2 ? 1u : 0u) + (g3 ? 1u : 0u);
        __builtin_nontemporal_store(o, &out[i]);
    }
    for (int off = 32; off > 0; off >>= 1) chi += __shfl_down(chi, off, 64);
    if (lane == 0) atomicAdd(&st[2], chi);
}

// ---------------- k2: read-only candidate extraction ----------------
__global__ void __launch_bounds__(256)
extract(const uint4* __restrict__ x, int n4, uint2* __restrict__ cand,
        unsigned* __restrict__ cntw, unsigned* __restrict__ st,
        unsigned lo_u, unsigned span)
{
    const unsigned lane = threadIdx.x & 63u;
    const unsigned tid  = (unsigned)(blockIdx.x * 256 + threadIdx.x);
    const unsigned wave = tid >> 6;
    uint2* seg = cand + (size_t)wave * SEG;
    unsigned ccnt = 0;
    int S = gridDim.x * 256;
    for (int i = (int)tid; i < n4; i += S) {
        uint4 v = x[i];
        unsigned gi = (unsigned)i * 4u;
        #define STEP(COMP, OFS) { \
            unsigned u = map_bits(v.COMP); \
            bool c = (u - lo_u) < span; \
            unsigned long long m = __ballot(c); \
            if (c) { unsigned pos = ccnt + (unsigned)__popcll(m & ((1ull << lane) - 1ull)); \
                     if (pos < SEG) seg[pos] = make_uint2(u, gi + OFS); } \
            ccnt += (unsigned)__popcll(m); }
        STEP(x, 0u) STEP(y, 1u) STEP(z, 2u) STEP(w, 3u)
        #undef STEP
    }
    if (lane == 0) {
        atomicAdd(&st[16], ccnt);
        atomicMax(&st[17], ccnt);
        cntw[wave] = ccnt;
    }
}

// ---------------- exact bracket verification (1 thread) ----------------
__global__ void flagcomp(unsigned n, unsigned r, unsigned* st)
{
    unsigned long long Nc  = st[16];
    unsigned long long Chi = st[2];
    unsigned long long Nlt_hi = (unsigned long long)n - Chi;   // #{u < hi}
    unsigned flag = 0;
    if (st[17] > SEG) flag = 1;                // segment overflow
    if (Nc > Nlt_hi)  flag = 1;
    unsigned long long Nlt_lo = (Nc > Nlt_hi) ? 0ull : (Nlt_hi - Nc);  // #{u < lo}
    if (!((Nlt_lo <= (unsigned long long)r) && ((unsigned long long)r < Nlt_hi)))
        flag = 1;
    st[3] = flag;
    st[4] = (unsigned)((unsigned long long)r - Nlt_lo);
}

// ---------------- candidate histograms (gated, flag==0) ----------------
__global__ void __launch_bounds__(256)
cand_histA(const uint2* __restrict__ cand, const unsigned* __restrict__ cntw,
           const unsigned* __restrict__ st, unsigned* __restrict__ hist,
           unsigned lo_u)
{
    if (st[3] != 0u) return;
    __shared__ unsigned lh[1024];
    for (int i = threadIdx.x; i < 1024; i += 256) lh[i] = 0u;
    __syncthreads();
    unsigned tid = (unsigned)(blockIdx.x * 256 + threadIdx.x);
    unsigned lane = tid & 63u;
    unsigned wave = tid >> 6;
    const uint2* seg = cand + (size_t)wave * SEG;
    unsigned m = cntw[wave]; if (m > SEG) m = SEG;
    for (unsigned j = lane; j < m; j += 64u)
        atomicAdd(&lh[(seg[j].x - lo_u) >> 10], 1u);
    __syncthreads();
    for (int i = threadIdx.x; i < 1024; i += 256) {
        unsigned c = lh[i];
        if (c) atomicAdd(&hist[i], c);
    }
}

__global__ void __launch_bounds__(256)
cand_histB(const uint2* __restrict__ cand, const unsigned* __restrict__ cntw,
           const unsigned* __restrict__ st, unsigned* __restrict__ hist,
           unsigned lo_u)
{
    if (st[3] != 0u) return;
    __shared__ unsigned lh[1024];
    for (int i = threadIdx.x; i < 1024; i += 256) lh[i] = 0u;
    __syncthreads();
    unsigned chunkA = st[5];
    unsigned tid = (unsigned)(blockIdx.x * 256 + threadIdx.x);
    unsigned lane = tid & 63u;
    unsigned wave = tid >> 6;
    const uint2* seg = cand + (size_t)wave * SEG;
    unsigned m = cntw[wave]; if (m > SEG) m = SEG;
    for (unsigned j = lane; j < m; j += 64u) {
        unsigned d = seg[j].x - lo_u;
        if ((d >> 10) == chunkA) atomicAdd(&lh[d & 0x3FFu], 1u);
    }
    __syncthreads();
    for (int i = threadIdx.x; i < 1024; i += 256) {
        unsigned c = lh[i];
        if (c) atomicAdd(&hist[i], c);
    }
}

// ---------------- generic gated single-block select ----------------
__global__ void __launch_bounds__(1024)
scan_select(const unsigned* __restrict__ hist, int nbins,
            const unsigned* __restrict__ rank_in, unsigned rank_imm,
            unsigned* __restrict__ bin_out, unsigned* __restrict__ rank_out,
            const unsigned* __restrict__ gate, int want_nonzero)
{
    if (gate) {
        unsigned g = *gate;
        if ((g != 0u) != (want_nonzero != 0)) return;
    }
    __shared__ unsigned s[1024];
    int t = threadIdx.x;
    unsigned rank = rank_in ? *rank_in : rank_imm;
    int per = (nbins + 1023) >> 10;
    int base = t * per;
    unsigned mySum = 0;
    for (int i = 0; i < per; ++i) {
        int b = base + i;
        if (b < nbins) mySum += hist[b];
    }
    s[t] = mySum;
    __syncthreads();
    for (int off = 1; off < 1024; off <<= 1) {
        unsigned v = (t >= off) ? s[t - off] : 0u;
        __syncthreads();
        s[t] += v;
        __syncthreads();
    }
    unsigned incl = s[t];
    unsigned excl = incl - mySum;
    if (rank >= excl && rank < incl) {
        unsigned run = excl;
        for (int i = 0; i < per; ++i) {
            int b = base + i;
            unsigned c = (b < nbins) ? hist[b] : 0u;
            if (rank < run + c) { *bin_out = (unsigned)b; *rank_out = rank - run; break; }
            run += c;
        }
    }
}

// ---------------- fixup (gated) ----------------
__global__ void __launch_bounds__(256)
fixup(const uint2* __restrict__ cand, const unsigned* __restrict__ cntw,
      const unsigned* __restrict__ st, float* __restrict__ out, unsigned lo_u)
{
    if (st[3] != 0u) return;
    unsigned thr = lo_u + (st[5] << 10) + st[7];
    unsigned tid = (unsigned)(blockIdx.x * 256 + threadIdx.x);
    unsigned lane = tid & 63u;
    unsigned wave = tid >> 6;
    const uint2* seg = cand + (size_t)wave * SEG;
    unsigned m = cntw[wave]; if (m > SEG) m = SEG;
    for (unsigned j = lane; j < m; j += 64u) {
        uint2 cv = seg[j];
        if (cv.x >= thr) out[cv.y] = 1.0f;
    }
}

// ---------------- fallback (proven 3-pass radix), flag-gated ----------------
__global__ void __launch_bounds__(256)
hist_pass(const uint4* __restrict__ x, int n4, int shift, int nbins, int mode,
          const unsigned* __restrict__ state, unsigned* __restrict__ hist,
          const unsigned* __restrict__ gate)
{
    if (gate && *gate == 0u) return;
    __shared__ unsigned lh[4096];
    for (int i = threadIdx.x; i < nbins; i += blockDim.x) lh[i] = 0u;
    __syncthreads();

    unsigned tgt = 0; int mshift = 0;
    if (mode == 1)      { tgt = state[0];                      mshift = 20; }
    else if (mode == 2) { tgt = (state[0] << 12) | state[2];   mshift = 8;  }

    const unsigned binmask = (unsigned)(nbins - 1);
    int idx = blockIdx.x * blockDim.x + threadIdx.x;
    int stride = gridDim.x * blockDim.x;
    for (int i = idx; i < n4; i += stride) {
        uint4 v = x[i];
        unsigned u;
        u = map_bits(v.x); if (!mode || (u >> mshift) == tgt) atomicAdd(&lh[(u >> shift) & binmask], 1u);
        u = map_bits(v.y); if (!mode || (u >> mshift) == tgt) atomicAdd(&lh[(u >> shift) & binmask], 1u);
        u = map_bits(v.z); if (!mode || (u >> mshift) == tgt) atomicAdd(&lh[(u >> shift) & binmask], 1u);
        u = map_bits(v.w); if (!mode || (u >> mshift) == tgt) atomicAdd(&lh[(u >> shift) & binmask], 1u);
    }
    __syncthreads();
    for (int i = threadIdx.x; i < nbins; i += blockDim.x) {
        unsigned c = lh[i];
        if (c) atomicAdd(&hist[i], c);
    }
}

__global__ void finalize_thr_fb(unsigned* st, const unsigned* gate) {
    if (gate && *gate == 0u) return;
    unsigned u = (st[10] << 20) | (st[12] << 8) | st[14];
    st[9] = (u & 0x80000000u) ? (u & 0x7FFFFFFFu) : ~u;
}

__global__ void __launch_bounds__(256)
mask_kernel(const float4* __restrict__ x, float4* __restrict__ out, int n4,
            const unsigned* __restrict__ st, const unsigned* __restrict__ gate)
{
    if (gate && *gate == 0u) return;
    float thr = __uint_as_float(st[9]);
    int idx = blockIdx.x * blockDim.x + threadIdx.x;
    int stride = gridDim.x * blockDim.x;
    for (int i = idx; i < n4; i += stride) {
        float4 v = x[i];
        float4 o;
        o.x = (v.x >= thr) ? 1.0f : 0.0f;
        o.y = (v.y >= thr) ? 1.0f : 0.0f;
        o.z = (v.z >= thr) ? 1.0f : 0.0f;
        o.w = (v.w >= thr) ? 1.0f : 0.0f;
        out[i] = o;
    }
}

// ---------------- host ----------------
static inline unsigned host_map(float f) {
    unsigned raw; memcpy(&raw, &f, 4);
    return (raw & 0x80000000u) ? ~raw : (raw | 0x80000000u);
}

extern "C" void kernel_launch(void* const* d_in, const int* in_sizes, int n_in,
                              void* d_out, int out_size, void* d_ws, size_t ws_size,
                              hipStream_t stream)
{
    const float* x = (const float*)d_in[0];
    float* out = (float*)d_out;
    long long n = (long long)in_sizes[0];
    long long k = (long long)((double)n * 0.9);   // matches Python int(n * RATIO)

    if (k <= 0) {
        hipMemsetAsync(d_out, 0, (size_t)out_size * sizeof(float), stream);
        return;
    }

    unsigned* ws = (unsigned*)d_ws;
    unsigned* st = ws;
    int n4 = (int)(n / 4);
    const uint4* x4 = (const uint4*)x;
    unsigned r = (unsigned)(n - k);               // ascending rank of threshold

    size_t need_fast = ((size_t)CAND_OFF + (size_t)NWAVES * SEG * 2) * 4;

    if (ws_size >= need_fast) {
        unsigned* hA   = ws + HA_OFF;
        unsigned* hB   = ws + HB_OFF;
        unsigned* fb1  = ws + FB1_OFF;
        unsigned* fb2  = ws + FB2_OFF;
        unsigned* fb3  = ws + FB3_OFF;
        unsigned* cntw = ws + CNTW_OFF;
        uint2*    cand = (uint2*)(ws + CAND_OFF);

        // Static bracket around the 0.1-quantile of N(0,1); exactness of the
        // final mask does NOT depend on it (flag-verified, fallback-gated).
        unsigned lo_u = host_map(-1.34f);
        unsigned hi_u = host_map(-1.22f);   // span = hi-lo < 2^20
        unsigned span = hi_u - lo_u;

        zero_small<<<16, 256, 0, stream>>>((uint4*)d_ws, FIXED_Z / 4);
        mask_only<<<2048, 256, 0, stream>>>(x4, n4, (vfloat4*)out, st, hi_u);
        extract<<<2048, 256, 0, stream>>>(x4, n4, cand, cntw, st, lo_u, span);
        flagcomp<<<1, 1, 0, stream>>>((unsigned)n, r, st);
        // fast-path select chain (gated on flag==0)
        cand_histA<<<2048, 256, 0, stream>>>(cand, cntw, st, hA, lo_u);
        scan_select<<<1, 1024, 0, stream>>>(hA, 1024, &st[4], 0u, &st[5], &st[6], &st[3], 0);
        cand_histB<<<2048, 256, 0, stream>>>(cand, cntw, st, hB, lo_u);
        scan_select<<<1, 1024, 0, stream>>>(hB, 1024, &st[6], 0u, &st[7], &st[8], &st[3], 0);
        fixup<<<2048, 256, 0, stream>>>(cand, cntw, st, out, lo_u);
        // fallback chain (gated on flag!=0) — proven exact path
        hist_pass<<<1024, 256, 0, stream>>>(x4, n4, 20, 4096, 0, &st[10], fb1, &st[3]);
        scan_select<<<1, 1024, 0, stream>>>(fb1, 4096, nullptr, r, &st[10], &st[11], &st[3], 1);
        hist_pass<<<1024, 256, 0, stream>>>(x4, n4, 8, 4096, 1, &st[10], fb2, &st[3]);
        scan_select<<<1, 1024, 0, stream>>>(fb2, 4096, &st[11], 0u, &st[12], &st[13], &st[3], 1);
        hist_pass<<<1024, 256, 0, stream>>>(x4, n4, 0, 256, 2, &st[10], fb3, &st[3]);
        scan_select<<<1, 1024, 0, stream>>>(fb3, 256, &st[13], 0u, &st[14], &st[15], &st[3], 1);
        finalize_thr_fb<<<1, 1, 0, stream>>>(st, &st[3]);
        mask_kernel<<<1024, 256, 0, stream>>>((const float4*)x, (float4*)out, n4, st, &st[3]);
    } else {
        // small-ws standalone fallback: 3-pass radix + mask (ungated)
        unsigned* h1 = ws + 16;
        unsigned* h2 = ws + 16 + 4096;
        unsigned* h3 = ws + 16 + 8192;

        hipMemsetAsync(d_ws, 0, FB_WS_INTS * sizeof(unsigned), stream);

        hist_pass<<<2048, 256, 0, stream>>>(x4, n4, 20, 4096, 0, &ws[10], h1, nullptr);
        scan_select<<<1, 1024, 0, stream>>>(h1, 4096, nullptr, r, &ws[10], &ws[11], nullptr, 0);
        hist_pass<<<2048, 256, 0, stream>>>(x4, n4, 8, 4096, 1, &ws[10], h2, nullptr);
        scan_select<<<1, 1024, 0, stream>>>(h2, 4096, &ws[11], 0u, &ws[12], &ws[13], nullptr, 0);
        hist_pass<<<2048, 256, 0, stream>>>(x4, n4, 0, 256, 2, &ws[10], h3, nullptr);
        scan_select<<<1, 1024, 0, stream>>>(h3, 256, &ws[13], 0u, &ws[14], &ws[15], nullptr, 0);
        finalize_thr_fb<<<1, 1, 0, stream>>>(ws, nullptr);
        mask_kernel<<<2048, 256, 0, stream>>>((const float4*)x, (float4*)out, n4, ws, nullptr);
    }
}

// Round 10
// 230.409 us; speedup vs baseline: 2.0559x; 2.0559x over previous
//
#include <hip/hip_runtime.h>
#include <string.h>

// Exact k-th order statistic + mask, fp32, n = 64*1024*1024.
// r3's proven structure with ONE change: the coarse bin b1 is static
// (the 2^20-wide bin containing the 0.1-quantile of N(0,1)), verified
// EXACTLY on-device; proven 3-pass radix fallback always enqueued, gated.
//
// state: [2]=chi [3]=flag [4]=r' [5]=chunkA [6]=rA [7]=thr_key
//        [9]=fb_thr [10..15]=fb chain
//
// ws layout (ints): ST(32) | H20(1M) | FB1(4096) | FB2(4096) | FB3(256)
//                   | PART(1024) | CNTW(8192) | CAND(8192 waves x 2048 x uint2)

#define N_STATE  32
#define H20_OFF  32
#define FB1_OFF  (H20_OFF + 1048576)
#define FB2_OFF  (FB1_OFF + 4096)
#define FB3_OFF  (FB2_OFF + 4096)
#define FIXED_Z  (FB3_OFF + 256)          // zeroed every call (~4.23 MB)
#define PART_OFF FIXED_Z
#define CNTW_OFF (PART_OFF + 1024)
#define NWAVES   8192
#define CAND_OFF (CNTW_OFF + NWAVES)
#define SEG      2048u

#define FB_WS_INTS (16 + 4096 + 4096 + 256)

__device__ __forceinline__ unsigned map_bits(unsigned raw) {
    return (raw & 0x80000000u) ? ~raw : (raw | 0x80000000u);
}

// ---------------- workspace zeroing ----------------
__global__ void __launch_bounds__(256)
zero_ws(uint4* __restrict__ p, int n16)
{
    int i = blockIdx.x * 256 + threadIdx.x;
    int s = gridDim.x * 256;
    uint4 z = make_uint4(0u, 0u, 0u, 0u);
    for (; i < n16; i += s) p[i] = z;
}

// ---------------- the single full pass (r3's pass2 + chi tally) ----------------
__device__ __forceinline__ void cand_step(unsigned u, unsigned gi, unsigned b1,
                                          unsigned* __restrict__ h20,
                                          uint2* __restrict__ seg,
                                          unsigned& cnt, unsigned& chi,
                                          unsigned lane, float& oc)
{
    unsigned p = u >> 20;
    bool gt = (p > b1);
    oc = gt ? 1.0f : 0.0f;
    chi += gt ? 1u : 0u;
    bool c = (p == b1);
    if (c) atomicAdd(&h20[u & 0xFFFFFu], 1u);          // no return -> no wait
    unsigned long long m = __ballot(c);
    if (c) {
        unsigned pos = cnt + (unsigned)__popcll(m & ((1ull << lane) - 1ull));
        if (pos < SEG) seg[pos] = make_uint2(u, gi);
    }
    cnt += (unsigned)__popcll(m);                       // wave-uniform, SGPR
}

__global__ void __launch_bounds__(256)
pass2(const uint4* __restrict__ x, int n4, float4* __restrict__ out,
      unsigned* __restrict__ h20, uint2* __restrict__ cand,
      unsigned* __restrict__ cnt_out, unsigned* __restrict__ st, unsigned b1)
{
    const unsigned lane = threadIdx.x & 63u;
    const unsigned wave = (unsigned)(blockIdx.x * blockDim.x + threadIdx.x) >> 6;
    uint2* seg = cand + (size_t)wave * SEG;
    unsigned cnt = 0;
    unsigned chi = 0;

    int idx = blockIdx.x * blockDim.x + threadIdx.x;
    int stride = gridDim.x * blockDim.x;
    for (int i = idx; i < n4; i += stride) {
        uint4 v = x[i];
        float4 o;
        unsigned gi = (unsigned)i * 4u;
        cand_step(map_bits(v.x), gi + 0u, b1, h20, seg, cnt, chi, lane, o.x);
        cand_step(map_bits(v.y), gi + 1u, b1, h20, seg, cnt, chi, lane, o.y);
        cand_step(map_bits(v.z), gi + 2u, b1, h20, seg, cnt, chi, lane, o.z);
        cand_step(map_bits(v.w), gi + 3u, b1, h20, seg, cnt, chi, lane, o.w);
        out[i] = o;
    }
    for (int off = 32; off > 0; off >>= 1) chi += __shfl_down(chi, off, 64);
    if (lane == 0) {
        atomicAdd(&st[2], chi);
        cnt_out[wave] = cnt;               // raw (uncapped) for overflow check
    }
}

// ---------------- exact bracket verification (1 block) ----------------
__global__ void __launch_bounds__(1024)
flagcomp(const unsigned* __restrict__ cntw, unsigned n, unsigned r,
         unsigned* __restrict__ st)
{
    __shared__ unsigned ssum[1024];
    __shared__ unsigned smax[1024];
    int t = threadIdx.x;
    unsigned sum = 0, mx = 0;
    for (int i = t; i < NWAVES; i += 1024) {
        unsigned c = cntw[i];
        sum += c; mx = (c > mx) ? c : mx;
    }
    ssum[t] = sum; smax[t] = mx;
    __syncthreads();
    for (int off = 512; off > 0; off >>= 1) {
        if (t < off) {
            ssum[t] += ssum[t + off];
            smax[t] = (smax[t + off] > smax[t]) ? smax[t + off] : smax[t];
        }
        __syncthreads();
    }
    if (t == 0) {
        unsigned long long Nc  = ssum[0];
        unsigned long long chi = st[2];
        unsigned long long Nlt_lo = (unsigned long long)n - chi - Nc;  // #{p < b1}
        unsigned flag = 0;
        if (smax[0] > SEG) flag = 1;
        if (!((Nlt_lo <= (unsigned long long)r) &&
              ((unsigned long long)r < Nlt_lo + Nc))) flag = 1;
        st[3] = flag;
        st[4] = (unsigned)((unsigned long long)r - Nlt_lo);
    }
}

// ---------------- refine-hist chunk reduction (gated) ----------------
__global__ void __launch_bounds__(256)
reduce_chunks(const unsigned* __restrict__ h20, unsigned* __restrict__ part,
              const unsigned* __restrict__ gate)
{
    if (*gate != 0u) return;
    __shared__ unsigned s[256];
    unsigned sum = 0;
    int base = blockIdx.x * 1024;
    for (int t = threadIdx.x; t < 1024; t += 256) sum += h20[base + t];
    s[threadIdx.x] = sum;
    __syncthreads();
    for (int off = 128; off > 0; off >>= 1) {
        if (threadIdx.x < off) s[threadIdx.x] += s[threadIdx.x + off];
        __syncthreads();
    }
    if (threadIdx.x == 0) part[blockIdx.x] = s[0];
}

// ---------------- fused 2-level select over h20 (gated) ----------------
__global__ void __launch_bounds__(1024)
scan20(const unsigned* __restrict__ h20, const unsigned* __restrict__ part,
       unsigned* __restrict__ st)
{
    if (st[3] != 0u) return;
    __shared__ unsigned s[1024];
    __shared__ unsigned sh_bin, sh_res;
    int t = threadIdx.x;

    // level A: chunks
    unsigned rank = st[4];
    unsigned v = part[t];
    s[t] = v;
    __syncthreads();
    for (int off = 1; off < 1024; off <<= 1) {
        unsigned w = (t >= off) ? s[t - off] : 0u;
        __syncthreads();
        s[t] += w;
        __syncthreads();
    }
    {
        unsigned incl = s[t], excl = incl - v;
        if (rank >= excl && rank < incl) { sh_bin = (unsigned)t; sh_res = rank - excl; }
    }
    __syncthreads();
    unsigned chunk = sh_bin;
    unsigned r2 = sh_res;
    __syncthreads();

    // level B: bins within chunk
    v = h20[(size_t)chunk * 1024 + t];
    s[t] = v;
    __syncthreads();
    for (int off = 1; off < 1024; off <<= 1) {
        unsigned w = (t >= off) ? s[t - off] : 0u;
        __syncthreads();
        s[t] += w;
        __syncthreads();
    }
    {
        unsigned incl = s[t], excl = incl - v;
        if (r2 >= excl && r2 < incl)
            st[7] = (chunk << 10) | (unsigned)t;   // low-20 key of threshold
    }
}

// ---------------- fixup (gated) ----------------
__global__ void __launch_bounds__(256)
fixup(const uint2* __restrict__ cand, const unsigned* __restrict__ cntw,
      const unsigned* __restrict__ st, float* __restrict__ out, unsigned b1)
{
    if (st[3] != 0u) return;
    unsigned thr = (b1 << 20) | st[7];
    unsigned tid = (unsigned)(blockIdx.x * 256 + threadIdx.x);
    unsigned lane = tid & 63u;
    unsigned wave = tid >> 6;
    const uint2* seg = cand + (size_t)wave * SEG;
    unsigned m = cntw[wave]; if (m > SEG) m = SEG;
    for (unsigned j = lane; j < m; j += 64u) {
        uint2 cv = seg[j];
        if (cv.x >= thr) out[cv.y] = 1.0f;
    }
}

// ---------------- fallback (proven 3-pass radix), flag-gated ----------------
__global__ void __launch_bounds__(256)
hist_pass(const uint4* __restrict__ x, int n4, int shift, int nbins, int mode,
          const unsigned* __restrict__ state, unsigned* __restrict__ hist,
          const unsigned* __restrict__ gate)
{
    if (gate && *gate == 0u) return;
    __shared__ unsigned lh[4096];
    for (int i = threadIdx.x; i < nbins; i += blockDim.x) lh[i] = 0u;
    __syncthreads();

    unsigned tgt = 0; int mshift = 0;
    if (mode == 1)      { tgt = state[0];                      mshift = 20; }
    else if (mode == 2) { tgt = (state[0] << 12) | state[2];   mshift = 8;  }

    const unsigned binmask = (unsigned)(nbins - 1);
    int idx = blockIdx.x * blockDim.x + threadIdx.x;
    int stride = gridDim.x * blockDim.x;
    for (int i = idx; i < n4; i += stride) {
        uint4 v = x[i];
        unsigned u;
        u = map_bits(v.x); if (!mode || (u >> mshift) == tgt) atomicAdd(&lh[(u >> shift) & binmask], 1u);
        u = map_bits(v.y); if (!mode || (u >> mshift) == tgt) atomicAdd(&lh[(u >> shift) & binmask], 1u);
        u = map_bits(v.z); if (!mode || (u >> mshift) == tgt) atomicAdd(&lh[(u >> shift) & binmask], 1u);
        u = map_bits(v.w); if (!mode || (u >> mshift) == tgt) atomicAdd(&lh[(u >> shift) & binmask], 1u);
    }
    __syncthreads();
    for (int i = threadIdx.x; i < nbins; i += blockDim.x) {
        unsigned c = lh[i];
        if (c) atomicAdd(&hist[i], c);
    }
}

__global__ void __launch_bounds__(1024)
scan_select(const unsigned* __restrict__ hist, int nbins,
            const unsigned* __restrict__ rank_in, unsigned rank_imm,
            unsigned* __restrict__ bin_out, unsigned* __restrict__ rank_out,
            const unsigned* __restrict__ gate, int want_nonzero)
{
    if (gate) {
        unsigned g = *gate;
        if ((g != 0u) != (want_nonzero != 0)) return;
    }
    __shared__ unsigned s[1024];
    int t = threadIdx.x;
    unsigned rank = rank_in ? *rank_in : rank_imm;
    int per = (nbins + 1023) >> 10;
    int base = t * per;
    unsigned mySum = 0;
    for (int i = 0; i < per; ++i) {
        int b = base + i;
        if (b < nbins) mySum += hist[b];
    }
    s[t] = mySum;
    __syncthreads();
    for (int off = 1; off < 1024; off <<= 1) {
        unsigned v = (t >= off) ? s[t - off] : 0u;
        __syncthreads();
        s[t] += v;
        __syncthreads();
    }
    unsigned incl = s[t];
    unsigned excl = incl - mySum;
    if (rank >= excl && rank < incl) {
        unsigned run = excl;
        for (int i = 0; i < per; ++i) {
            int b = base + i;
            unsigned c = (b < nbins) ? hist[b] : 0u;
            if (rank < run + c) { *bin_out = (unsigned)b; *rank_out = rank - run; break; }
            run += c;
        }
    }
}

__global__ void finalize_thr_fb(unsigned* st, const unsigned* gate) {
    if (gate && *gate == 0u) return;
    unsigned u = (st[10] << 20) | (st[12] << 8) | st[14];
    st[9] = (u & 0x80000000u) ? (u & 0x7FFFFFFFu) : ~u;
}

__global__ void __launch_bounds__(256)
mask_kernel(const float4* __restrict__ x, float4* __restrict__ out, int n4,
            const unsigned* __restrict__ st, const unsigned* __restrict__ gate)
{
    if (gate && *gate == 0u) return;
    float thr = __uint_as_float(st[9]);
    int idx = blockIdx.x * blockDim.x + threadIdx.x;
    int stride = gridDim.x * blockDim.x;
    for (int i = idx; i < n4; i += stride) {
        float4 v = x[i];
        float4 o;
        o.x = (v.x >= thr) ? 1.0f : 0.0f;
        o.y = (v.y >= thr) ? 1.0f : 0.0f;
        o.z = (v.z >= thr) ? 1.0f : 0.0f;
        o.w = (v.w >= thr) ? 1.0f : 0.0f;
        out[i] = o;
    }
}

// ---------------- host ----------------
static inline unsigned host_map(float f) {
    unsigned raw; memcpy(&raw, &f, 4);
    return (raw & 0x80000000u) ? ~raw : (raw | 0x80000000u);
}

extern "C" void kernel_launch(void* const* d_in, const int* in_sizes, int n_in,
                              void* d_out, int out_size, void* d_ws, size_t ws_size,
                              hipStream_t stream)
{
    const float* x = (const float*)d_in[0];
    float* out = (float*)d_out;
    long long n = (long long)in_sizes[0];
    long long k = (long long)((double)n * 0.9);   // matches Python int(n * RATIO)

    if (k <= 0) {
        hipMemsetAsync(d_out, 0, (size_t)out_size * sizeof(float), stream);
        return;
    }

    unsigned* ws = (unsigned*)d_ws;
    unsigned* st = ws;
    int n4 = (int)(n / 4);
    const uint4* x4 = (const uint4*)x;
    unsigned r = (unsigned)(n - k);               // ascending rank of threshold

    size_t need_fast = (size_t)CAND_OFF * 4 + (size_t)NWAVES * SEG * 8;

    if (ws_size >= need_fast) {
        unsigned* h20  = ws + H20_OFF;
        unsigned* fb1  = ws + FB1_OFF;
        unsigned* fb2  = ws + FB2_OFF;
        unsigned* fb3  = ws + FB3_OFF;
        unsigned* part = ws + PART_OFF;
        unsigned* cntw = ws + CNTW_OFF;
        uint2*    cand = (uint2*)(ws + CAND_OFF);

        // Static coarse bin: the 2^20-wide bin containing the 0.1-quantile of
        // N(0,1) (x in (-1.375, -1.25], prob mass 0.0846..0.1056 straddles 0.1).
        // Exactness does NOT depend on this: flag-verified, fallback-gated.
        unsigned B1 = host_map(-1.2816f) >> 20;

        zero_ws<<<512, 256, 0, stream>>>((uint4*)d_ws, FIXED_Z / 4);
        pass2<<<2048, 256, 0, stream>>>(x4, n4, (float4*)out, h20, cand, cntw, st, B1);
        flagcomp<<<1, 1024, 0, stream>>>(cntw, (unsigned)n, r, st);
        // fast-path select chain (gated on flag==0)
        reduce_chunks<<<1024, 256, 0, stream>>>(h20, part, &st[3]);
        scan20<<<1, 1024, 0, stream>>>(h20, part, st);
        fixup<<<2048, 256, 0, stream>>>(cand, cntw, st, out, B1);
        // fallback chain (gated on flag!=0) — proven exact path
        hist_pass<<<1024, 256, 0, stream>>>(x4, n4, 20, 4096, 0, &st[10], fb1, &st[3]);
        scan_select<<<1, 1024, 0, stream>>>(fb1, 4096, nullptr, r, &st[10], &st[11], &st[3], 1);
        hist_pass<<<1024, 256, 0, stream>>>(x4, n4, 8, 4096, 1, &st[10], fb2, &st[3]);
        scan_select<<<1, 1024, 0, stream>>>(fb2, 4096, &st[11], 0u, &st[12], &st[13], &st[3], 1);
        hist_pass<<<1024, 256, 0, stream>>>(x4, n4, 0, 256, 2, &st[10], fb3, &st[3]);
        scan_select<<<1, 1024, 0, stream>>>(fb3, 256, &st[13], 0u, &st[14], &st[15], &st[3], 1);
        finalize_thr_fb<<<1, 1, 0, stream>>>(st, &st[3]);
        mask_kernel<<<1024, 256, 0, stream>>>((const float4*)x, (float4*)out, n4, st, &st[3]);
    } else {
        // small-ws standalone fallback: 3-pass radix + mask (ungated)
        unsigned* h1 = ws + 16;
        unsigned* h2 = ws + 16 + 4096;
        unsigned* h3 = ws + 16 + 8192;

        hipMemsetAsync(d_ws, 0, FB_WS_INTS * sizeof(unsigned), stream);

        hist_pass<<<2048, 256, 0, stream>>>(x4, n4, 20, 4096, 0, &ws[10], h1, nullptr);
        scan_select<<<1, 1024, 0, stream>>>(h1, 4096, nullptr, r, &ws[10], &ws[11], nullptr, 0);
        hist_pass<<<2048, 256, 0, stream>>>(x4, n4, 8, 4096, 1, &ws[10], h2, nullptr);
        scan_select<<<1, 1024, 0, stream>>>(h2, 4096, &ws[11], 0u, &ws[12], &ws[13], nullptr, 0);
        hist_pass<<<2048, 256, 0, stream>>>(x4, n4, 0, 256, 2, &ws[10], h3, nullptr);
        scan_select<<<1, 1024, 0, stream>>>(h3, 256, &ws[13], 0u, &ws[14], &ws[15], nullptr, 0);
        finalize_thr_fb<<<1, 1, 0, stream>>>(ws, nullptr);
        mask_kernel<<<2048, 256, 0, stream>>>((const float4*)x, (float4*)out, n4, ws, nullptr);
    }
}